// Round 2
// baseline (316.989 us; speedup 1.0000x reference)
//
#include <hip/hip_runtime.h>

// ---------- types ----------
typedef __attribute__((ext_vector_type(8))) _Float16 half8;
typedef __attribute__((ext_vector_type(2))) __fp16 half2r;   // cvt_pkrtz return type
typedef __attribute__((ext_vector_type(4))) float f32x4;

#define AS1 __attribute__((address_space(1)))
#define AS3 __attribute__((address_space(3)))

union H2U { half2r h; unsigned int u; };
union Frag { half8 v; unsigned long long d[2]; };

__device__ __forceinline__ unsigned int pk(float a, float b) {
    H2U x; x.h = __builtin_amdgcn_cvt_pkrtz(a, b); return x.u;
}

__device__ __forceinline__ void gload_lds16(const void* g, void* l) {
    __builtin_amdgcn_global_load_lds((const AS1 unsigned int*)g,
                                     (AS3 unsigned int*)l, 16, 0, 0);
}

// ---------- problem constants ----------
// M = B*T = 32768, D_STATE = 1088, D_MODEL = 1024, D_LATENT = 128
#define W1_ROWB 2176           // 17 slabs * 128 B per row (f16, swizzled)
#define WS2_OFF 2228224        // 1024 * 2176
#define W2_ROWB 256            // 2 slabs * 128 B

// pick the fused-add source for k-step ks (ks is wave-uniform)
__device__ __forceinline__ void pick_w(int ks, const float* wsp, const float* whp,
                                       const float* whs, const float* wtg,
                                       const float*& wbase, int& wstr, int& wko) {
    if (ks < 8)       { wbase = wsp; wstr = 512; wko = ks * 64; }
    else if (ks < 12) { wbase = whp; wstr = 256; wko = ks * 64 - 512; }
    else if (ks < 16) { wbase = whs; wstr = 256; wko = ks * 64 - 768; }
    else              { wbase = wtg; wstr = 64;  wko = 0; }
}

// ============ prologue: convert weights to f16, pre-swizzled ============
// layout: row n, byte = n*ROWB + (k/64)*128 + ( (2*(k%64)) ^ ((n&7)<<4) )
__global__ __launch_bounds__(256) void prep_w(const float* __restrict__ Wr,
                                              const float* __restrict__ Wk,
                                              const float* __restrict__ Wv,
                                              char* __restrict__ ws) {
    int id = blockIdx.x * 256 + threadIdx.x;
    if (id < 272 * 1024) {                       // W_read: 1024 x 1088
        int n = id / 272;
        int k = (id % 272) * 4;
        f32x4 w = *(const f32x4*)(Wr + (size_t)n * 1088 + k);
        uint2 q; q.x = pk(w.x, w.y); q.y = pk(w.z, w.w);
        size_t off = (size_t)n * W1_ROWB + ((k >> 6) << 7)
                   + (((k & 63) << 1) ^ ((n & 7) << 4));
        *(uint2*)(ws + off) = q;
    } else {                                     // Wk|Wv combined: 2048 x 128
        int j = id - 272 * 1024;                 // grid sized exactly
        int r = j >> 5;                          // 0..2047
        int k = (j & 31) << 2;                   // 0..124
        const float* src = (r < 1024) ? (Wk + (size_t)r * 128 + k)
                                      : (Wv + (size_t)(r - 1024) * 128 + k);
        f32x4 w = *(const f32x4*)src;
        uint2 q; q.x = pk(w.x, w.y); q.y = pk(w.z, w.w);
        size_t off = WS2_OFF + (size_t)r * W2_ROWB + ((k >> 6) << 7)
                   + (((k & 63) << 1) ^ ((r & 7) << 4));
        *(uint2*)(ws + off) = q;
    }
}

// ============ GEMM1 (fused): out = cvt(S + w) @ W_read^T ============
// A is NOT materialized: each K-step reg-loads S and the matching w slice in
// f32, adds, cvt_pkrtz -> f16, ds_writes swizzled into the LDS A buffer.
// The add+cvt VALU work rides in the MFMA-bound loop's idle VALU cycles.
__global__ __launch_bounds__(256, 2)
void gemm_read_f(const float* __restrict__ S, const float* __restrict__ wsp,
                 const float* __restrict__ whp, const float* __restrict__ whs,
                 const float* __restrict__ wtg, const char* __restrict__ wws,
                 float* __restrict__ out) {
    __shared__ char lds[65536];
    // A0=lds, A1=+16384, B0=+32768, B1=+49152

    int bid = blockIdx.x;
    int wg   = (bid & 7) * 256 + (bid >> 3);     // bijective XCD swizzle (2048%8==0)
    int mblk = wg >> 3, nblk = wg & 7;
    int m0 = mblk << 7, n0 = nblk << 7;

    int tid = threadIdx.x;
    int lane = tid & 63, wid = tid >> 6;
    int wm = (wid >> 1) << 6, wn = (wid & 1) << 6;   // wave sub-tile origin
    int lp = lane & 15, lg = lane >> 4;

    f32x4 acc[4][4] = {};
    f32x4 sreg[8], wreg[8];

    // A-unit mapping: unit u = c*256 + tid; row = u>>4 (0..127); k4 = (u&15)<<2.
    // 16 lanes cover one row's 64 f32 (256 B contiguous) -> coalesced.
#define LOAD_A(KS) do {                                                       \
        const float* wbase; int wstr, wko;                                    \
        pick_w((KS), wsp, whp, whs, wtg, wbase, wstr, wko);                   \
        _Pragma("unroll")                                                     \
        for (int c = 0; c < 8; ++c) {                                         \
            int u = c * 256 + tid;                                            \
            int row = u >> 4;                                                 \
            int k4 = (u & 15) << 2;                                           \
            sreg[c] = *(const f32x4*)(S + (size_t)(m0 + row) * 1088           \
                                        + (KS) * 64 + k4);                    \
            wreg[c] = *(const f32x4*)(wbase + (size_t)(m0 + row) * wstr       \
                                        + wko + k4);                          \
        }                                                                     \
    } while (0)

#define WRITE_A(DL) do {                                                      \
        _Pragma("unroll")                                                     \
        for (int c = 0; c < 8; ++c) {                                         \
            int u = c * 256 + tid;                                            \
            int row = u >> 4;                                                 \
            int k4 = (u & 15) << 2;                                           \
            uint2 q; q.x = pk(sreg[c].x + wreg[c].x, sreg[c].y + wreg[c].y);  \
                     q.y = pk(sreg[c].z + wreg[c].z, sreg[c].w + wreg[c].w);  \
            *(uint2*)((DL) + (row << 7) + ((k4 << 1) ^ ((row & 7) << 4))) = q;\
        }                                                                     \
    } while (0)

#define STAGE_B(KS, DL) do {                                                  \
        const char* grow = wws + (size_t)n0 * W1_ROWB + (KS) * 128;           \
        _Pragma("unroll")                                                     \
        for (int c = 0; c < 4; ++c) {                                         \
            int s = c * 4096 + wid * 1024 + lane * 16;                        \
            int rr = s >> 7, cb = s & 127;                                    \
            gload_lds16(grow + (size_t)rr * W1_ROWB + cb,                     \
                        (DL) + c * 4096 + wid * 1024);                        \
        }                                                                     \
    } while (0)

#define COMPUTE(AL, BL) do {                                                  \
        _Pragma("unroll")                                                     \
        for (int b = 0; b < 2; ++b) {                                         \
            Frag af[4], bf[4];                                                \
            _Pragma("unroll")                                                 \
            for (int f = 0; f < 4; ++f) {                                     \
                int ra = wm + f * 16 + lp;  int xa = (ra & 7) << 4;           \
                af[f].d[0] = *(const unsigned long long*)((AL) + (ra << 7) + ((b * 64 + lg * 8) ^ xa));      \
                af[f].d[1] = *(const unsigned long long*)((AL) + (ra << 7) + ((b * 64 + 32 + lg * 8) ^ xa)); \
                int rb = wn + f * 16 + lp;  int xb = (rb & 7) << 4;           \
                bf[f].d[0] = *(const unsigned long long*)((BL) + (rb << 7) + ((b * 64 + lg * 8) ^ xb));      \
                bf[f].d[1] = *(const unsigned long long*)((BL) + (rb << 7) + ((b * 64 + 32 + lg * 8) ^ xb)); \
            }                                                                 \
            _Pragma("unroll")                                                 \
            for (int i = 0; i < 4; ++i)                                       \
                _Pragma("unroll")                                             \
                for (int j = 0; j < 4; ++j)                                   \
                    acc[i][j] = __builtin_amdgcn_mfma_f32_16x16x32_f16(af[i].v, bf[j].v, acc[i][j], 0, 0, 0); \
        }                                                                     \
    } while (0)

    // prologue: fill buffer 0
    LOAD_A(0);
    STAGE_B(0, lds + 32768);
    WRITE_A(lds);
    __syncthreads();

    for (int ks = 0; ks < 17; ++ks) {
        int co = (ks & 1) ? 16384 : 0;
        int no = co ^ 16384;
        if (ks < 16) {
            LOAD_A(ks + 1);                       // issue early: hides under MFMA
            STAGE_B(ks + 1, lds + 32768 + no);
        }
        COMPUTE(lds + co, lds + 32768 + co);
        if (ks < 16) WRITE_A(lds + no);           // waitcnt lands after compute
        __syncthreads();
    }

    // epilogue: C[row = wm+i*16+lg*4+r][col = wn+j*16+lp]
    #pragma unroll
    for (int i = 0; i < 4; ++i)
        #pragma unroll
        for (int j = 0; j < 4; ++j) {
            int row = m0 + wm + i * 16 + (lg << 2);
            int col = n0 + wn + j * 16 + lp;
            float* p = out + (size_t)row * 1024 + col;
            #pragma unroll
            for (int r = 0; r < 4; ++r) p[(size_t)r * 1024] = acc[i][j][r];
        }
#undef LOAD_A
#undef WRITE_A
#undef STAGE_B
#undef COMPUTE
}

// ============ GEMM2: k = latent@Wk^T, v = latent@Wv^T (N fused = 2048) ====
__global__ __launch_bounds__(256, 2)
void gemm_kv(const float* __restrict__ lat, const char* __restrict__ ws2,
             float* __restrict__ outk, float* __restrict__ outv) {
    __shared__ char lds[32768];
    char* Al = lds;
    char* Bl = lds + 16384;

    int bid = blockIdx.x;
    int wg   = (bid & 7) * 512 + (bid >> 3);     // 4096 % 8 == 0
    int mblk = wg >> 4, nb = wg & 15;
    int m0 = mblk << 7;
    int nrow0 = nb << 7;                          // row in combined Wk|Wv
    float* out = (nb < 8) ? outk : outv;
    int n0 = (nb & 7) << 7;

    int tid = threadIdx.x;
    int lane = tid & 63, wid = tid >> 6;
    int wm = (wid >> 1) << 6, wn = (wid & 1) << 6;
    int lp = lane & 15, lg = lane >> 4;

    f32x4 acc[4][4] = {};

    for (int ks = 0; ks < 2; ++ks) {
        __syncthreads();
        {
            const char* wrow = ws2 + (size_t)nrow0 * W2_ROWB + ks * 128;
            #pragma unroll
            for (int c = 0; c < 4; ++c) {
                int s = c * 4096 + wid * 1024 + lane * 16;
                int n = s >> 7, cb = s & 127;
                gload_lds16(wrow + (size_t)n * W2_ROWB + cb,
                            Bl + c * 4096 + wid * 1024);
            }
        }
        #pragma unroll
        for (int i = 0; i < 8; ++i) {
            int u = i * 256 + tid;
            int row = u >> 4;
            int k4 = (u & 15) << 2;
            f32x4 s4 = *(const f32x4*)(lat + (size_t)(m0 + row) * 128 + ks * 64 + k4);
            uint2 q; q.x = pk(s4.x, s4.y); q.y = pk(s4.z, s4.w);
            *(uint2*)(Al + (row << 7) + ((k4 << 1) ^ ((row & 7) << 4))) = q;
        }
        __syncthreads();

        #pragma unroll
        for (int b = 0; b < 2; ++b) {
            Frag af[4], bf[4];
            #pragma unroll
            for (int f = 0; f < 4; ++f) {
                int ra = wm + f * 16 + lp;  int xa = (ra & 7) << 4;
                af[f].d[0] = *(const unsigned long long*)(Al + (ra << 7) + ((b * 64 + lg * 8) ^ xa));
                af[f].d[1] = *(const unsigned long long*)(Al + (ra << 7) + ((b * 64 + 32 + lg * 8) ^ xa));
                int rb = wn + f * 16 + lp;  int xb = (rb & 7) << 4;
                bf[f].d[0] = *(const unsigned long long*)(Bl + (rb << 7) + ((b * 64 + lg * 8) ^ xb));
                bf[f].d[1] = *(const unsigned long long*)(Bl + (rb << 7) + ((b * 64 + 32 + lg * 8) ^ xb));
            }
            #pragma unroll
            for (int i = 0; i < 4; ++i)
                #pragma unroll
                for (int j = 0; j < 4; ++j)
                    acc[i][j] = __builtin_amdgcn_mfma_f32_16x16x32_f16(af[i].v, bf[j].v, acc[i][j], 0, 0, 0);
        }
    }

    #pragma unroll
    for (int i = 0; i < 4; ++i)
        #pragma unroll
        for (int j = 0; j < 4; ++j) {
            int row = m0 + wm + i * 16 + (lg << 2);
            int col = n0 + wn + j * 16 + lp;
            float* p = out + (size_t)row * 1024 + col;
            #pragma unroll
            for (int r = 0; r < 4; ++r) p[(size_t)r * 1024] = acc[i][j][r];
        }
}

// ============ host ============
extern "C" void kernel_launch(void* const* d_in, const int* in_sizes, int n_in,
                              void* d_out, int out_size, void* d_ws, size_t ws_size,
                              hipStream_t stream) {
    const float* S   = (const float*)d_in[0];
    const float* wsp = (const float*)d_in[1];
    const float* whp = (const float*)d_in[2];
    const float* whs = (const float*)d_in[3];
    const float* wtg = (const float*)d_in[4];
    const float* Wr  = (const float*)d_in[5];
    // d_in[6] = cache: fully overwritten by latent -> dead input
    const float* lat = (const float*)d_in[7];
    const float* Wk  = (const float*)d_in[8];
    const float* Wv  = (const float*)d_in[9];
    float* out = (float*)d_out;
    char*  ws  = (char*)d_ws;

    float* outk = out + 33554432ull;
    float* outv = out + 67108864ull;

    // 3 launches; no Af16 intermediate at all (the fuse-add is folded into
    // gemm_read_f's A staging -> saves 142 MB HBM round-trip + one kernel).
    hipLaunchKernelGGL(prep_w, dim3(1344), dim3(256), 0, stream, Wr, Wk, Wv, ws);
    hipLaunchKernelGGL(gemm_read_f, dim3(2048), dim3(256), 0, stream,
                       S, wsp, whp, whs, wtg, ws, out);
    hipLaunchKernelGGL(gemm_kv, dim3(4096), dim3(256), 0, stream,
                       lat, ws + WS2_OFF, outk, outv);
}

// Round 3
// 270.728 us; speedup vs baseline: 1.1709x; 1.1709x over previous
//
#include <hip/hip_runtime.h>

// ---------- types ----------
typedef __attribute__((ext_vector_type(8))) _Float16 half8;
typedef __attribute__((ext_vector_type(2))) __fp16 half2r;   // cvt_pkrtz return type
typedef __attribute__((ext_vector_type(4))) float f32x4;

#define AS1 __attribute__((address_space(1)))
#define AS3 __attribute__((address_space(3)))

union H2U { half2r h; unsigned int u; };
union Frag { half8 v; unsigned long long d[2]; };

__device__ __forceinline__ unsigned int pk(float a, float b) {
    H2U x; x.h = __builtin_amdgcn_cvt_pkrtz(a, b); return x.u;
}

__device__ __forceinline__ void gload_lds16(const void* g, void* l) {
    __builtin_amdgcn_global_load_lds((const AS1 unsigned int*)g,
                                     (AS3 unsigned int*)l, 16, 0, 0);
}

// ---------- problem constants ----------
// M = B*T = 32768, D_STATE = 1088, D_MODEL = 1024, D_LATENT = 128
// W1/A layout (BK=32 granularity): row r, f32-elem k lives (as f16 pair-unit
// of 4 elems, 8 B) at byte r*2176 + (k/32)*64 + (((k/4)&7) ^ (r&7))*8.
#define W1_ROWB 2176           // 34 slabs * 64 B per row (f16, swizzled)
#define WS2_OFF 2228224        // 1024 * 2176
#define W2_ROWB 256            // kv weights: OLD layout, 2 slabs * 128 B
#define A_ROWB  2176           // Af16 row: same slab layout as W_read

// pick the fused-add source for k-step ks (128-wide slab index, 0..16)
__device__ __forceinline__ void pick_w(int ks, const float* wsp, const float* whp,
                                       const float* whs, const float* wtg,
                                       const float*& wbase, int& wstr, int& wko) {
    if (ks < 8)       { wbase = wsp; wstr = 512; wko = ks * 64; }
    else if (ks < 12) { wbase = whp; wstr = 256; wko = ks * 64 - 512; }
    else if (ks < 16) { wbase = whs; wstr = 256; wko = ks * 64 - 768; }
    else              { wbase = wtg; wstr = 64;  wko = 0; }
}

// ============ prologue: convert weights to f16, pre-swizzled ============
__global__ __launch_bounds__(256) void prep_w(const float* __restrict__ Wr,
                                              const float* __restrict__ Wk,
                                              const float* __restrict__ Wv,
                                              char* __restrict__ ws) {
    int id = blockIdx.x * 256 + threadIdx.x;
    if (id < 272 * 1024) {                       // W_read: 1024 x 1088, NEW layout
        int n = id / 272;
        int k = (id % 272) * 4;
        f32x4 w = *(const f32x4*)(Wr + (size_t)n * 1088 + k);
        uint2 q; q.x = pk(w.x, w.y); q.y = pk(w.z, w.w);
        size_t off = (size_t)n * W1_ROWB + ((k >> 5) << 6)
                   + ((((k >> 2) & 7) ^ (n & 7)) << 3);
        *(uint2*)(ws + off) = q;
    } else {                                     // Wk|Wv combined: 2048 x 128, OLD layout
        int j = id - 272 * 1024;                 // grid sized exactly
        int r = j >> 5;                          // 0..2047
        int k = (j & 31) << 2;                   // 0..124
        const float* src = (r < 1024) ? (Wk + (size_t)r * 128 + k)
                                      : (Wv + (size_t)(r - 1024) * 128 + k);
        f32x4 w = *(const f32x4*)src;
        uint2 q; q.x = pk(w.x, w.y); q.y = pk(w.z, w.w);
        size_t off = WS2_OFF + (size_t)r * W2_ROWB + ((k >> 6) << 7)
                   + (((k & 63) << 1) ^ ((r & 7) << 4));
        *(uint2*)(ws + off) = q;
    }
}

// ============ pass 1: Af16[m][k] = cvt(S + w), NEW pre-swizzled layout ============
// unit = one uint2 (4 f32 -> 4 f16). 32768 rows * 272 units = 8,912,896
__global__ __launch_bounds__(256)
void fuse_a(const float* __restrict__ S, const float* __restrict__ wsp,
            const float* __restrict__ whp, const float* __restrict__ whs,
            const float* __restrict__ wtg, char* __restrict__ a16) {
    int u = blockIdx.x * 256 + threadIdx.x;
    int row = u / 272;
    int rem = u % 272;
    int ks = rem >> 4;                           // 128-wide slab for w-source pick
    int k4 = (rem & 15) << 2;                    // 0..60 within 128-slab

    const float* wbase; int wstr, wko;
    pick_w(ks, wsp, whp, whs, wtg, wbase, wstr, wko);

    f32x4 s4 = *(const f32x4*)(S + (size_t)row * 1088 + ks * 64 + k4);
    f32x4 w4 = *(const f32x4*)(wbase + (size_t)row * wstr + wko + k4);
    uint2 q; q.x = pk(s4.x + w4.x, s4.y + w4.y);
             q.y = pk(s4.z + w4.z, s4.w + w4.w);
    int kk = ks * 64 + k4;                       // global f32 k index
    size_t off = (size_t)row * A_ROWB + ((kk >> 5) << 6)
               + ((((kk >> 2) & 7) ^ (row & 7)) << 3);
    *(uint2*)(a16 + off) = q;
}

// ============ GEMM1: out = Af16 @ W_read^T, BK=32, 32 KB LDS, 4 blocks/CU ====
__global__ __launch_bounds__(256, 4)
void gemm_read(const char* __restrict__ wsA, const char* __restrict__ wws,
               float* __restrict__ out) {
    __shared__ char lds[32768];
    // A0=0, A1=8192, B0=16384, B1=24576 (tile = 128 rows x 64 B)

    int bid = blockIdx.x;
    int wg   = (bid & 7) * 256 + (bid >> 3);     // bijective XCD swizzle (2048%8==0)
    int mblk = wg >> 3, nblk = wg & 7;
    int m0 = mblk << 7, n0 = nblk << 7;

    int tid = threadIdx.x;
    int lane = tid & 63, wid = tid >> 6;
    int wm = (wid >> 1) << 6, wn = (wid & 1) << 6;   // wave sub-tile origin
    int lp = lane & 15, lg = lane >> 4;

    f32x4 acc[4][4] = {};

    // stage one 8 KB tile (128 rows x 64 B): 2 chunks of 16 B per thread
#define STAGE32(T, DL, BASE, ROWB, R0) do {                               \
        const char* grow = (BASE) + (size_t)(R0) * (ROWB) + (T) * 64;     \
        _Pragma("unroll")                                                 \
        for (int c = 0; c < 2; ++c) {                                     \
            int s = c * 4096 + wid * 1024 + lane * 16;                    \
            int rr = s >> 6, cb = s & 63;                                 \
            gload_lds16(grow + (size_t)rr * (ROWB) + cb,                  \
                        (DL) + c * 4096 + wid * 1024);                    \
        }                                                                 \
    } while (0)

    // one K=32 step: frag unit u (8B) of row r sits at (u ^ (r&7))*8
#define COMPUTE32(AL, BL) do {                                            \
        Frag af[4], bf[4];                                                \
        _Pragma("unroll")                                                 \
        for (int f = 0; f < 4; ++f) {                                     \
            int ra = wm + f * 16 + lp;  int xa = ra & 7;                  \
            af[f].d[0] = *(const unsigned long long*)((AL) + (ra << 6) + ((lg ^ xa) << 3));        \
            af[f].d[1] = *(const unsigned long long*)((AL) + (ra << 6) + (((4 + lg) ^ xa) << 3));  \
            int rb = wn + f * 16 + lp;  int xb = rb & 7;                  \
            bf[f].d[0] = *(const unsigned long long*)((BL) + (rb << 6) + ((lg ^ xb) << 3));        \
            bf[f].d[1] = *(const unsigned long long*)((BL) + (rb << 6) + (((4 + lg) ^ xb) << 3));  \
        }                                                                 \
        _Pragma("unroll")                                                 \
        for (int i = 0; i < 4; ++i)                                       \
            _Pragma("unroll")                                             \
            for (int j = 0; j < 4; ++j)                                   \
                acc[i][j] = __builtin_amdgcn_mfma_f32_16x16x32_f16(af[i].v, bf[j].v, acc[i][j], 0, 0, 0); \
    } while (0)

    // prologue: fill buffer 0
    STAGE32(0, lds,         wsA, A_ROWB,  m0);
    STAGE32(0, lds + 16384, wws, W1_ROWB, n0);
    __syncthreads();

    for (int t = 0; t < 34; ++t) {
        int co = (t & 1) ? 8192 : 0;
        int no = co ^ 8192;
        if (t < 33) {
            STAGE32(t + 1, lds + no,         wsA, A_ROWB,  m0);
            STAGE32(t + 1, lds + 16384 + no, wws, W1_ROWB, n0);
        }
        COMPUTE32(lds + co, lds + 16384 + co);
        __syncthreads();
    }

    // epilogue: C[row = wm+i*16+lg*4+r][col = wn+j*16+lp]
    #pragma unroll
    for (int i = 0; i < 4; ++i)
        #pragma unroll
        for (int j = 0; j < 4; ++j) {
            int row = m0 + wm + i * 16 + (lg << 2);
            int col = n0 + wn + j * 16 + lp;
            float* p = out + (size_t)row * 1024 + col;
            #pragma unroll
            for (int r = 0; r < 4; ++r) p[(size_t)r * 1024] = acc[i][j][r];
        }
#undef STAGE32
#undef COMPUTE32
}

// ============ GEMM2: k = latent@Wk^T, v = latent@Wv^T (N fused = 2048) ====
// unchanged from the R0 baseline (OLD 128B-slab layout)
__global__ __launch_bounds__(256, 2)
void gemm_kv(const float* __restrict__ lat, const char* __restrict__ ws2,
             float* __restrict__ outk, float* __restrict__ outv) {
    __shared__ char lds[32768];
    char* Al = lds;
    char* Bl = lds + 16384;

    int bid = blockIdx.x;
    int wg   = (bid & 7) * 512 + (bid >> 3);     // 4096 % 8 == 0
    int mblk = wg >> 4, nb = wg & 15;
    int m0 = mblk << 7;
    int nrow0 = nb << 7;                          // row in combined Wk|Wv
    float* out = (nb < 8) ? outk : outv;
    int n0 = (nb & 7) << 7;

    int tid = threadIdx.x;
    int lane = tid & 63, wid = tid >> 6;
    int wm = (wid >> 1) << 6, wn = (wid & 1) << 6;
    int lp = lane & 15, lg = lane >> 4;

    f32x4 acc[4][4] = {};

    for (int ks = 0; ks < 2; ++ks) {
        __syncthreads();
        {
            const char* wrow = ws2 + (size_t)nrow0 * W2_ROWB + ks * 128;
            #pragma unroll
            for (int c = 0; c < 4; ++c) {
                int s = c * 4096 + wid * 1024 + lane * 16;
                int n = s >> 7, cb = s & 127;
                gload_lds16(wrow + (size_t)n * W2_ROWB + cb,
                            Bl + c * 4096 + wid * 1024);
            }
        }
        #pragma unroll
        for (int i = 0; i < 8; ++i) {
            int u = i * 256 + tid;
            int row = u >> 4;
            int k4 = (u & 15) << 2;
            f32x4 s4 = *(const f32x4*)(lat + (size_t)(m0 + row) * 128 + ks * 64 + k4);
            uint2 q; q.x = pk(s4.x, s4.y); q.y = pk(s4.z, s4.w);
            *(uint2*)(Al + (row << 7) + ((k4 << 1) ^ ((row & 7) << 4))) = q;
        }
        __syncthreads();

        #pragma unroll
        for (int b = 0; b < 2; ++b) {
            Frag af[4], bf[4];
            #pragma unroll
            for (int f = 0; f < 4; ++f) {
                int ra = wm + f * 16 + lp;  int xa = (ra & 7) << 4;
                af[f].d[0] = *(const unsigned long long*)(Al + (ra << 7) + ((b * 64 + lg * 8) ^ xa));
                af[f].d[1] = *(const unsigned long long*)(Al + (ra << 7) + ((b * 64 + 32 + lg * 8) ^ xa));
                int rb = wn + f * 16 + lp;  int xb = (rb & 7) << 4;
                bf[f].d[0] = *(const unsigned long long*)(Bl + (rb << 7) + ((b * 64 + lg * 8) ^ xb));
                bf[f].d[1] = *(const unsigned long long*)(Bl + (rb << 7) + ((b * 64 + 32 + lg * 8) ^ xb));
            }
            #pragma unroll
            for (int i = 0; i < 4; ++i)
                #pragma unroll
                for (int j = 0; j < 4; ++j)
                    acc[i][j] = __builtin_amdgcn_mfma_f32_16x16x32_f16(af[i].v, bf[j].v, acc[i][j], 0, 0, 0);
        }
    }

    #pragma unroll
    for (int i = 0; i < 4; ++i)
        #pragma unroll
        for (int j = 0; j < 4; ++j) {
            int row = m0 + wm + i * 16 + (lg << 2);
            int col = n0 + wn + j * 16 + lp;
            float* p = out + (size_t)row * 1024 + col;
            #pragma unroll
            for (int r = 0; r < 4; ++r) p[(size_t)r * 1024] = acc[i][j][r];
        }
}

// ============ host ============
extern "C" void kernel_launch(void* const* d_in, const int* in_sizes, int n_in,
                              void* d_out, int out_size, void* d_ws, size_t ws_size,
                              hipStream_t stream) {
    const float* S   = (const float*)d_in[0];
    const float* wsp = (const float*)d_in[1];
    const float* whp = (const float*)d_in[2];
    const float* whs = (const float*)d_in[3];
    const float* wtg = (const float*)d_in[4];
    const float* Wr  = (const float*)d_in[5];
    // d_in[6] = cache: fully overwritten by latent -> dead input
    const float* lat = (const float*)d_in[7];
    const float* Wk  = (const float*)d_in[8];
    const float* Wv  = (const float*)d_in[9];
    float* out = (float*)d_out;
    char*  ws  = (char*)d_ws;

    // Af16 scratch lives in the v-region of d_out (128 MB >= 71 MB);
    // gemm_kv overwrites it afterwards (stream-ordered, deterministic).
    char* a16 = (char*)(out + 67108864ull);

    hipLaunchKernelGGL(prep_w, dim3(1344), dim3(256), 0, stream, Wr, Wk, Wv, ws);
    hipLaunchKernelGGL(fuse_a, dim3(34816), dim3(256), 0, stream,
                       S, wsp, whp, whs, wtg, a16);
    hipLaunchKernelGGL(gemm_read, dim3(2048), dim3(256), 0, stream,
                       a16, ws, out);
    hipLaunchKernelGGL(gemm_kv, dim3(4096), dim3(256), 0, stream,
                       lat, ws + WS2_OFF, out + 33554432ull, out + 67108864ull);
}